// Round 3
// baseline (216.009 us; speedup 1.0000x reference)
//
#include <hip/hip_runtime.h>

#define D 128
#define EC 1024      // edges per binning chunk
#define BSH 8        // bin shift: bin = dst >> 8, 256 nodes per bin
#define CAP 5120     // per-bin edge capacity (expect 4096 +- 64; 16-sigma margin)
#define HPAD 136     // h_neigh LDS row stride in shorts (128 + 8 pad -> 2-way banks max)
#define CSTR 16      // bin_cursor stride in ints (64B -> one counter per cache line)

typedef __attribute__((ext_vector_type(8))) short bf16x8;
typedef __attribute__((ext_vector_type(4))) float f32x4;

__device__ __forceinline__ unsigned short f2bf(float f) {
    union { float f; unsigned int u; } c;
    c.f = f;
    unsigned int lsb = (c.u >> 16) & 1u;
    c.u += 0x7fffu + lsb;
    return (unsigned short)(c.u >> 16);
}

__device__ __forceinline__ float bf_lo(unsigned int x) {
    union { unsigned int u; float f; } c;
    c.u = x << 16;
    return c.f;
}
__device__ __forceinline__ float bf_hi(unsigned int x) {
    union { unsigned int u; float f; } c;
    c.u = x & 0xffff0000u;
    return c.f;
}

// ---------------------------------------------------------------- fused prep
// blocks [0, castB): cast feat -> fb (bf16)
// blocks [castB, castB+16): Wcat -> Wfrag in MFMA B-fragment order
// block castB+16: zero bin_cursor (256 x CSTR ints)
__global__ __launch_bounds__(256) void prep_kernel(const float* __restrict__ feat,
                                                   unsigned short* __restrict__ fb,
                                                   const float* __restrict__ Ws,
                                                   const float* __restrict__ Wn,
                                                   unsigned short* __restrict__ Wfrag,
                                                   int* __restrict__ bin_cursor,
                                                   int castB, int n8) {
    int bid = blockIdx.x;
    int t   = threadIdx.x;
    if (bid < castB) {
        int i = bid * 256 + t;
        if (i >= n8) return;
        const float4* s = (const float4*)(feat + (size_t)i * 8);
        float4 a = s[0];
        float4 b = s[1];
        unsigned short pk[8];
        pk[0] = f2bf(a.x); pk[1] = f2bf(a.y); pk[2] = f2bf(a.z); pk[3] = f2bf(a.w);
        pk[4] = f2bf(b.x); pk[5] = f2bf(b.y); pk[6] = f2bf(b.z); pk[7] = f2bf(b.w);
        *(bf16x8*)(fb + (size_t)i * 8) = *(const bf16x8*)pk;
    } else if (bid < castB + 16) {
        // Wfrag[((nt*8+ks)*64 + lane)*8 + j] = bf16(Wcat[ks*32+quad*8+j][nt*16+lo16])
        int tid = (bid - castB) * 256 + t;      // 0..4095
        int l  = tid & 63;
        int ks = (tid >> 6) & 7;
        int nt = tid >> 9;
        int n  = nt * 16 + (l & 15);
        int kb = ks * 32 + (l >> 4) * 8;
        unsigned short pk[8];
#pragma unroll
        for (int j = 0; j < 8; ++j) {
            int k = kb + j;
            float w = (k < 128) ? Ws[k * D + n] : Wn[(k - 128) * D + n];
            pk[j] = f2bf(w);
        }
        *(bf16x8*)(Wfrag + (size_t)tid * 8) = *(const bf16x8*)pk;
    } else {
#pragma unroll
        for (int j = 0; j < CSTR; ++j)
            bin_cursor[j * 256 + t] = 0;
    }
}

// ---------------------------------------------------------------- bin scatter (one pass)
// LDS histogram of this chunk's bins; reserve a contiguous range in bin b's
// fixed-capacity segment (one global atomic per block-bin, line-padded cursor);
// write edges packed (dstLocal<<16 | src) into ebuf[b*CAP + ...]. Overflow-guarded.
__global__ __launch_bounds__(256) void binscatter_kernel(const int* __restrict__ src,
                                                         const int* __restrict__ dst,
                                                         int* __restrict__ bin_cursor,
                                                         unsigned int* __restrict__ ebuf,
                                                         int E, int NB) {
    __shared__ int cnt[256];
    __shared__ int basev[256];
    __shared__ int cur[256];
    int t = threadIdx.x;
    cnt[t] = 0;
    cur[t] = 0;
    __syncthreads();
    int base = blockIdx.x * EC;
    int dr[EC / 256];
#pragma unroll
    for (int i = 0; i < EC / 256; ++i) {
        int e = base + i * 256 + t;
        dr[i] = (e < E) ? dst[e] : -1;
        if (dr[i] >= 0) atomicAdd(&cnt[dr[i] >> BSH], 1);
    }
    __syncthreads();
    if (t < NB && cnt[t]) basev[t] = atomicAdd(&bin_cursor[t * CSTR], cnt[t]);
    __syncthreads();
#pragma unroll
    for (int i = 0; i < EC / 256; ++i) {
        int e = base + i * 256 + t;
        if (dr[i] >= 0) {
            int d = dr[i];
            int b = d >> BSH;
            int loc = basev[b] + atomicAdd(&cur[b], 1);
            if (loc < CAP)
                ebuf[(size_t)b * CAP + loc] =
                    (unsigned int)src[e] | ((unsigned int)(d & ((1 << BSH) - 1)) << 16);
        }
    }
}

// ---------------------------------------------------------------- per-bin CSR
// One 1024-thread block per bin; segment [b*CAP, b*CAP + cnt). All bookkeeping
// in LDS; bucket (ushort) written into the same strided segment; rs points into it.
__global__ __launch_bounds__(1024) void csrbin_kernel(const unsigned int* __restrict__ ebuf,
                                                      const int* __restrict__ bin_cursor,
                                                      int* __restrict__ rs_g,
                                                      int* __restrict__ deg_g,
                                                      unsigned short* __restrict__ bucket,
                                                      int N) {
    __shared__ int degL[256];
    __shared__ int scn[256];
    __shared__ int cur[256];
    int b = blockIdx.x;
    int t = threadIdx.x;
    int cntb = bin_cursor[b * CSTR];
    if (cntb > CAP) cntb = CAP;
    int s  = b * CAP;
    int e2 = s + cntb;

    if (t < 256) { degL[t] = 0; cur[t] = 0; }
    __syncthreads();
    for (int i = s + t; i < e2; i += 1024)
        atomicAdd(&degL[(ebuf[i] >> 16) & 255], 1);
    __syncthreads();

    if (t < 256) scn[t] = degL[t];
    __syncthreads();
    for (int off = 1; off < 256; off <<= 1) {
        int add = 0;
        if (t < 256 && t >= off) add = scn[t - off];
        __syncthreads();
        if (t < 256) scn[t] += add;
        __syncthreads();
    }

    for (int i = s + t; i < e2; i += 1024) {
        unsigned int p = ebuf[i];
        int dl = (p >> 16) & 255;
        int sl = atomicAdd(&cur[dl], 1);
        bucket[s + (scn[dl] - degL[dl]) + sl] = (unsigned short)(p & 0xffffu);
    }

    if (t < 256) {
        int node = (b << BSH) + t;
        if (node < N) {
            rs_g[node]  = s + scn[t] - degL[t];
            deg_g[node] = degL[t];
        }
    }
}

// ---------------------------------------------------------------- fused gather + MFMA
// One block = 4 waves (256 thr) = 16 groups of 16 lanes = 64 nodes.
// Phase 1 (gather): each GROUP owns its own node (16 concurrent latency chains
// per wave, vs 1 before). Per node: one ushort bucket load per lane (<=16 edge
// indices in one instruction), broadcast within the group via __shfl, then all
// <=16 edge rows issued back-to-back (16 uint4 in flight per lane) before any
// accumulate. Group owns the whole 128-col row -> NO cross-group reduce; group
// writes its mean row (bf16) straight into LDS hL. d is group-uniform; inter-
// group divergence on the d>16 remainder chunk (~44% of nodes) is accepted.
// Phase 2 (MFMA): out[M,128] = [fb | hL] @ Wcat + b. Wave w computes rows
// [w*16,+16) x all 128 cols: 8 ks x 8 nt MFMAs. A-frags ks<4 from fb (seq,
// L2-friendly), ks>=4 from LDS. B-frags from Wfrag (L2-hot).
__global__ __launch_bounds__(256) void gather_mfma_kernel(
        const unsigned short* __restrict__ fb,
        const unsigned short* __restrict__ bucket,
        const int* __restrict__ rs,
        const int* __restrict__ deg,
        const unsigned short* __restrict__ Wfrag,
        const float* __restrict__ bias,
        float* __restrict__ out, int N) {
    __shared__ unsigned short hL[64 * HPAD];

    int t    = threadIdx.x;
    int lane = t & 63;
    int c    = t & 15;          // col-slot within group (cols c*8 .. c*8+7)
    int G    = t >> 4;          // block-wide group id 0..15
    int v0   = blockIdx.x * 64;

    // ---- phase 1: each group gathers 4 nodes serially, 16 groups concurrent ----
    for (int it = 0; it < 4; ++it) {
        int node = v0 + it * 16 + G;
        int ncl  = (node < N) ? node : N - 1;
        int d    = deg[ncl];
        int base = rs[ncl];
        if (node >= N) d = 0;

        float acc[8];
#pragma unroll
        for (int j = 0; j < 8; ++j) acc[j] = 0.f;

        for (int i0 = 0; i0 < d; i0 += 16) {
            int m = d - i0; if (m > 16) m = 16;       // group-uniform
            int uc = (c < m) ? (int)bucket[base + i0 + c] : 0;
            uint4 rr[16];
#pragma unroll
            for (int e = 0; e < 16; ++e) {
                if (e < m) {
                    int ue = __shfl(uc, (lane & 48) + e);   // bcast within group
                    rr[e] = *(const uint4*)(fb + (size_t)ue * D + c * 8);
                }
            }
#pragma unroll
            for (int e = 0; e < 16; ++e) {
                if (e < m) {
                    acc[0] += bf_lo(rr[e].x); acc[1] += bf_hi(rr[e].x);
                    acc[2] += bf_lo(rr[e].y); acc[3] += bf_hi(rr[e].y);
                    acc[4] += bf_lo(rr[e].z); acc[5] += bf_hi(rr[e].z);
                    acc[6] += bf_lo(rr[e].w); acc[7] += bf_hi(rr[e].w);
                }
            }
        }

        float inv = (d > 0) ? 1.0f / (float)d : 0.0f;
        unsigned short pk[8];
#pragma unroll
        for (int j = 0; j < 8; ++j) pk[j] = f2bf(acc[j] * inv);
        *(bf16x8*)&hL[(it * 16 + G) * HPAD + c * 8] = *(const bf16x8*)pk;
    }
    __syncthreads();

    // ---- phase 2: MFMA epilogue (4 waves, wave w owns rows [w*16,+16)) ----
    int w    = t >> 6;
    int lo16 = lane & 15;
    int quad = lane >> 4;
    int rowA = v0 + w * 16 + lo16;
    if (rowA > N - 1) rowA = N - 1;           // clamp; stores guarded below
    int lrow = w * 16 + lo16;

    f32x4 accO[8];
#pragma unroll
    for (int nt = 0; nt < 8; ++nt) accO[nt] = (f32x4){0.f, 0.f, 0.f, 0.f};

#pragma unroll
    for (int ks = 0; ks < 8; ++ks) {
        bf16x8 a;
        if (ks < 4)
            a = *(const bf16x8*)(fb + (size_t)rowA * D + ks * 32 + quad * 8);
        else
            a = *(const bf16x8*)&hL[lrow * HPAD + (ks - 4) * 32 + quad * 8];
        const unsigned short* wp = Wfrag + ((size_t)ks * 64 + lane) * 8;
#pragma unroll
        for (int nt = 0; nt < 8; ++nt) {
            bf16x8 b = *(const bf16x8*)(wp + (size_t)nt * 4096);
            accO[nt] = __builtin_amdgcn_mfma_f32_16x16x32_bf16(a, b, accO[nt], 0, 0, 0);
        }
    }

    // C/D layout: col = lane&15, row = quad*4 + reg
#pragma unroll
    for (int nt = 0; nt < 8; ++nt) {
        int n = nt * 16 + lo16;
        float bvl = bias[n];
#pragma unroll
        for (int r = 0; r < 4; ++r) {
            int row = v0 + w * 16 + quad * 4 + r;
            if (row < N) out[(size_t)row * D + n] = accO[nt][r] + bvl;
        }
    }
}

extern "C" void kernel_launch(void* const* d_in, const int* in_sizes, int n_in,
                              void* d_out, int out_size, void* d_ws, size_t ws_size,
                              hipStream_t stream) {
    const float* feat = (const float*)d_in[0];
    const int*   src  = (const int*)d_in[1];
    const int*   dst  = (const int*)d_in[2];
    const float* Ws   = (const float*)d_in[3];
    const float* Wn   = (const float*)d_in[4];
    const float* bias = (const float*)d_in[5];
    float*       out  = (float*)d_out;

    const int N  = in_sizes[0] / D;
    const int E  = in_sizes[1];
    const int NB = (N + (1 << BSH) - 1) >> BSH;      // bins of 256 nodes
    const int nchunk = (E + EC - 1) / EC;
    const int castB  = (N * D / 8 + 255) / 256;

    // ws layout: ints: bin_cursor[256*CSTR] | rs[N] | deg[N] | ebuf[NB*CAP] ;
    //   then bucket[NB*CAP] (ushort) | fb[N*D] | Wfrag[32768] (bf16)
    int* bin_cursor = (int*)d_ws;
    int* rs         = bin_cursor + 256 * CSTR;
    int* deg        = rs + N;
    unsigned int* ebuf = (unsigned int*)(deg + N);
    unsigned short* bucket = (unsigned short*)(ebuf + (size_t)NB * CAP);
    size_t short_count = (size_t)NB * CAP;
    short_count = (short_count + 7) & ~(size_t)7;    // 16B-align what follows
    unsigned short* fb    = bucket + short_count;
    unsigned short* Wfrag = fb + (size_t)N * D;

    prep_kernel<<<castB + 17, 256, 0, stream>>>(feat, fb, Ws, Wn, Wfrag, bin_cursor,
                                                castB, N * D / 8);
    binscatter_kernel<<<nchunk, 256, 0, stream>>>(src, dst, bin_cursor, ebuf, E, NB);
    csrbin_kernel<<<NB, 1024, 0, stream>>>(ebuf, bin_cursor, rs, deg, bucket, N);
    gather_mfma_kernel<<<(N + 63) / 64, 256, 0, stream>>>(fb, bucket, rs, deg, Wfrag,
                                                          bias, out, N);
}

// Round 5
// 175.488 us; speedup vs baseline: 1.2309x; 1.2309x over previous
//
#include <hip/hip_runtime.h>

#define D 128
#define CAPN 64      // per-node bucket capacity (in-deg ~ Poisson(16); P(d>=64) ~ 2e-18)
#define HPAD 136     // h_neigh LDS row stride in shorts (128 + 8 pad)

typedef __attribute__((ext_vector_type(8))) short bf16x8;
typedef __attribute__((ext_vector_type(4))) float f32x4;

__device__ __forceinline__ unsigned short f2bf(float f) {
    union { float f; unsigned int u; } c;
    c.f = f;
    unsigned int lsb = (c.u >> 16) & 1u;
    c.u += 0x7fffu + lsb;
    return (unsigned short)(c.u >> 16);
}

__device__ __forceinline__ float bf_lo(unsigned int x) {
    union { unsigned int u; float f; } c;
    c.u = x << 16;
    return c.f;
}
__device__ __forceinline__ float bf_hi(unsigned int x) {
    union { unsigned int u; float f; } c;
    c.u = x & 0xffff0000u;
    return c.f;
}

// ---------------------------------------------------------------- fused prep
// blocks [0, castB): cast feat -> fb (bf16)
// blocks [castB, castB+16): Wcat -> Wfrag in MFMA B-fragment order
// blocks [castB+16, castB+16+zeroB): zero deg[N]
__global__ __launch_bounds__(256) void prep_kernel(const float* __restrict__ feat,
                                                   unsigned short* __restrict__ fb,
                                                   const float* __restrict__ Ws,
                                                   const float* __restrict__ Wn,
                                                   unsigned short* __restrict__ Wfrag,
                                                   int* __restrict__ deg,
                                                   int castB, int n8, int N) {
    int bid = blockIdx.x;
    int t   = threadIdx.x;
    if (bid < castB) {
        int i = bid * 256 + t;
        if (i >= n8) return;
        const float4* s = (const float4*)(feat + (size_t)i * 8);
        float4 a = s[0];
        float4 b = s[1];
        unsigned short pk[8];
        pk[0] = f2bf(a.x); pk[1] = f2bf(a.y); pk[2] = f2bf(a.z); pk[3] = f2bf(a.w);
        pk[4] = f2bf(b.x); pk[5] = f2bf(b.y); pk[6] = f2bf(b.z); pk[7] = f2bf(b.w);
        *(bf16x8*)(fb + (size_t)i * 8) = *(const bf16x8*)pk;
    } else if (bid < castB + 16) {
        // Wfrag[((nt*8+ks)*64 + lane)*8 + j] = bf16(Wcat[ks*32+quad*8+j][nt*16+lo16])
        int tid = (bid - castB) * 256 + t;      // 0..4095
        int l  = tid & 63;
        int ks = (tid >> 6) & 7;
        int nt = tid >> 9;
        int n  = nt * 16 + (l & 15);
        int kb = ks * 32 + (l >> 4) * 8;
        unsigned short pk[8];
#pragma unroll
        for (int j = 0; j < 8; ++j) {
            int k = kb + j;
            float w = (k < 128) ? Ws[k * D + n] : Wn[(k - 128) * D + n];
            pk[j] = f2bf(w);
        }
        *(bf16x8*)(Wfrag + (size_t)tid * 8) = *(const bf16x8*)pk;
    } else {
        int i = (bid - castB - 16) * 256 + t;
        if (i < N) deg[i] = 0;
    }
}

// ---------------------------------------------------------------- edge scatter
// One pass, no staging: per edge, claim a slot in dst's fixed 64-entry bucket.
// deg[] doubles as the per-node cursor and the final in-degree.
__global__ __launch_bounds__(256) void edge_kernel(const int* __restrict__ src,
                                                   const int* __restrict__ dst,
                                                   int* __restrict__ deg,
                                                   unsigned short* __restrict__ bucket,
                                                   int E) {
    int e = blockIdx.x * 256 + threadIdx.x;
    if (e >= E) return;
    int d = dst[e];
    int s = src[e];
    int loc = atomicAdd(&deg[d], 1);
    if (loc < CAPN)
        bucket[(size_t)d * CAPN + loc] = (unsigned short)s;
}

// ---------------------------------------------------------------- fused gather + MFMA
// One block = 4 waves (256 thr) = 16 nodes; wave w gathers nodes [v0+w*4, +4)
// serially. Per node the whole 64-entry index row is ONE coalesced ushort load
// (bucket[node*64+lane]), prefetched one node ahead; per-edge indices come from
// register __shfl. CRITICAL (R4 bug): the edge loop trip count must be
// WAVE-UNIFORM and all __shfl must execute with the full wave active --
// ds_bpermute returns 0 from exec-masked-off source lanes, so a per-group
// `for (i=g; i<d; i+=16)` loop corrupts reads once groups diverge on d.
// Here: uniform `for (i0=0; i0<d; i0+=16)`, shfls first (all lanes), then
// per-group bound-checked loads/accumulates.
// Phase 2: out[16,128] = [fb | hL] @ Wcat + b; wave w owns cols [w*32, +32):
// 8 ks x 2 nt MFMAs. B-frags from Wfrag (L2-hot).
__global__ __launch_bounds__(256) void gather_mfma_kernel(
        const unsigned short* __restrict__ fb,
        const unsigned short* __restrict__ bucket,
        const int* __restrict__ deg,
        const unsigned short* __restrict__ Wfrag,
        const float* __restrict__ bias,
        float* __restrict__ out, int N) {
    __shared__ unsigned short hL[16 * HPAD];

    int t    = threadIdx.x;
    int w    = t >> 6;
    int lane = t & 63;
    int g    = lane >> 4;       // group = edge-slot phase
    int c    = lane & 15;       // col-slot (cols c*8 .. c*8+7)
    int v0   = blockIdx.x * 16;
    int n0   = v0 + w * 4;

    // lanes 0..3 hold deg of nodes n0..n0+3 (replicated every 4 lanes)
    int nd  = n0 + (lane & 3);
    int dn  = (nd < N) ? deg[nd] : 0;
    int idx_cur = (n0 < N) ? (int)bucket[(size_t)n0 * CAPN + lane] : 0;

    for (int nn = 0; nn < 4; ++nn) {
        int node  = n0 + nn;                    // wave-uniform
        int dtrue = __shfl(dn, nn);             // full wave active
        int d     = (node < N) ? dtrue : 0;
        if (d > CAPN) d = CAPN;
        // prefetch next node's index row during this node's accumulation
        int idx_next = (nn < 3 && node + 1 < N)
                     ? (int)bucket[(size_t)(node + 1) * CAPN + lane] : 0;

        float acc[8];
#pragma unroll
        for (int j = 0; j < 8; ++j) acc[j] = 0.f;

        // wave-uniform trip count; all shfls execute with full wave active
        for (int i0 = 0; i0 < d; i0 += 16) {
            int i  = i0 + g;                    // this group's base slot
            int u0 = __shfl(idx_cur, i & 63);
            int u1 = __shfl(idx_cur, (i + 4) & 63);
            int u2 = __shfl(idx_cur, (i + 8) & 63);
            int u3 = __shfl(idx_cur, (i + 12) & 63);
            bool b0 = (i < d), b1 = (i + 4 < d), b2 = (i + 8 < d), b3 = (i + 12 < d);
            uint4 x0, x1, x2, x3;
            if (b0) x0 = *(const uint4*)(fb + (size_t)u0 * D + c * 8);
            if (b1) x1 = *(const uint4*)(fb + (size_t)u1 * D + c * 8);
            if (b2) x2 = *(const uint4*)(fb + (size_t)u2 * D + c * 8);
            if (b3) x3 = *(const uint4*)(fb + (size_t)u3 * D + c * 8);
            if (b0) {
                acc[0] += bf_lo(x0.x); acc[1] += bf_hi(x0.x);
                acc[2] += bf_lo(x0.y); acc[3] += bf_hi(x0.y);
                acc[4] += bf_lo(x0.z); acc[5] += bf_hi(x0.z);
                acc[6] += bf_lo(x0.w); acc[7] += bf_hi(x0.w);
            }
            if (b1) {
                acc[0] += bf_lo(x1.x); acc[1] += bf_hi(x1.x);
                acc[2] += bf_lo(x1.y); acc[3] += bf_hi(x1.y);
                acc[4] += bf_lo(x1.z); acc[5] += bf_hi(x1.z);
                acc[6] += bf_lo(x1.w); acc[7] += bf_hi(x1.w);
            }
            if (b2) {
                acc[0] += bf_lo(x2.x); acc[1] += bf_hi(x2.x);
                acc[2] += bf_lo(x2.y); acc[3] += bf_hi(x2.y);
                acc[4] += bf_lo(x2.z); acc[5] += bf_hi(x2.z);
                acc[6] += bf_lo(x2.w); acc[7] += bf_hi(x2.w);
            }
            if (b3) {
                acc[0] += bf_lo(x3.x); acc[1] += bf_hi(x3.x);
                acc[2] += bf_lo(x3.y); acc[3] += bf_hi(x3.y);
                acc[4] += bf_lo(x3.z); acc[5] += bf_hi(x3.z);
                acc[6] += bf_lo(x3.w); acc[7] += bf_hi(x3.w);
            }
        }

#pragma unroll
        for (int j = 0; j < 8; ++j) {
            acc[j] += __shfl_xor(acc[j], 16);
            acc[j] += __shfl_xor(acc[j], 32);
        }

        if (g == 0) {
            float inv = (d > 0) ? 1.0f / (float)dtrue : 0.0f;
            unsigned short pk[8];
#pragma unroll
            for (int j = 0; j < 8; ++j) pk[j] = f2bf(acc[j] * inv);
            *(bf16x8*)&hL[(w * 4 + nn) * HPAD + c * 8] = *(const bf16x8*)pk;
        }
        idx_cur = idx_next;
    }
    __syncthreads();

    // ---- phase 2: MFMA (16 rows x 128 cols; wave w owns cols [w*32, +32)) ----
    int lo16 = lane & 15;
    int quad = lane >> 4;
    int rowA = v0 + lo16;
    if (rowA > N - 1) rowA = N - 1;           // clamp; stores guarded below

    f32x4 accO[2];
#pragma unroll
    for (int ntl = 0; ntl < 2; ++ntl) accO[ntl] = (f32x4){0.f, 0.f, 0.f, 0.f};

#pragma unroll
    for (int ks = 0; ks < 8; ++ks) {
        bf16x8 a;
        if (ks < 4)
            a = *(const bf16x8*)(fb + (size_t)rowA * D + ks * 32 + quad * 8);
        else
            a = *(const bf16x8*)&hL[lo16 * HPAD + (ks - 4) * 32 + quad * 8];
        const unsigned short* wp = Wfrag + ((size_t)ks * 64 + lane) * 8;
#pragma unroll
        for (int ntl = 0; ntl < 2; ++ntl) {
            int nt = w * 2 + ntl;
            bf16x8 b = *(const bf16x8*)(wp + (size_t)nt * 4096);
            accO[ntl] = __builtin_amdgcn_mfma_f32_16x16x32_bf16(a, b, accO[ntl], 0, 0, 0);
        }
    }

    // C/D layout: col = lane&15, row = quad*4 + reg
#pragma unroll
    for (int ntl = 0; ntl < 2; ++ntl) {
        int n = (w * 2 + ntl) * 16 + lo16;
        float bvl = bias[n];
#pragma unroll
        for (int r = 0; r < 4; ++r) {
            int row = v0 + quad * 4 + r;
            if (row < N) out[(size_t)row * D + n] = accO[ntl][r] + bvl;
        }
    }
}

extern "C" void kernel_launch(void* const* d_in, const int* in_sizes, int n_in,
                              void* d_out, int out_size, void* d_ws, size_t ws_size,
                              hipStream_t stream) {
    const float* feat = (const float*)d_in[0];
    const int*   src  = (const int*)d_in[1];
    const int*   dst  = (const int*)d_in[2];
    const float* Ws   = (const float*)d_in[3];
    const float* Wn   = (const float*)d_in[4];
    const float* bias = (const float*)d_in[5];
    float*       out  = (float*)d_out;

    const int N = in_sizes[0] / D;
    const int E = in_sizes[1];
    const int castB = (N * D / 8 + 255) / 256;
    const int zeroB = (N + 255) / 256;

    // ws layout: ints: deg[N] ; then bucket[N*CAPN] (ushort) | fb[N*D] | Wfrag[32768] (bf16)
    int* deg = (int*)d_ws;
    unsigned short* bucket = (unsigned short*)(deg + N);
    size_t short_count = (size_t)N * CAPN;
    short_count = (short_count + 7) & ~(size_t)7;    // 16B-align what follows
    unsigned short* fb    = bucket + short_count;
    unsigned short* Wfrag = fb + (size_t)N * D;

    prep_kernel<<<castB + 16 + zeroB, 256, 0, stream>>>(feat, fb, Ws, Wn, Wfrag, deg,
                                                        castB, N * D / 8, N);
    edge_kernel<<<(E + 255) / 256, 256, 0, stream>>>(src, dst, deg, bucket, E);
    gather_mfma_kernel<<<(N + 15) / 16, 256, 0, stream>>>(fb, bucket, deg, Wfrag,
                                                          bias, out, N);
}

// Round 6
// 173.086 us; speedup vs baseline: 1.2480x; 1.0139x over previous
//
#include <hip/hip_runtime.h>

#define D 128
#define CAPN 64      // per-node bucket capacity (in-deg ~ Poisson(16); P(d>=64) ~ 2e-18)
#define HPAD 136     // h_neigh LDS row stride in shorts (128 + 8 pad)

typedef __attribute__((ext_vector_type(8))) short bf16x8;
typedef __attribute__((ext_vector_type(4))) float f32x4;

__device__ __forceinline__ unsigned short f2bf(float f) {
    union { float f; unsigned int u; } c;
    c.f = f;
    unsigned int lsb = (c.u >> 16) & 1u;
    c.u += 0x7fffu + lsb;
    return (unsigned short)(c.u >> 16);
}

__device__ __forceinline__ float bf_lo(unsigned int x) {
    union { unsigned int u; float f; } c;
    c.u = x << 16;
    return c.f;
}
__device__ __forceinline__ float bf_hi(unsigned int x) {
    union { unsigned int u; float f; } c;
    c.u = x & 0xffff0000u;
    return c.f;
}

// ---------------------------------------------------------------- fused prep
// blocks [0, castB): cast feat -> fb (bf16)
// blocks [castB, castB+16): Wcat -> Wfrag in MFMA B-fragment order
// blocks [castB+16, castB+16+zeroB): zero deg[N]; first block also zeroes
//   fb row N (the dummy zero row used by the gather's padded loads)
__global__ __launch_bounds__(256) void prep_kernel(const float* __restrict__ feat,
                                                   unsigned short* __restrict__ fb,
                                                   const float* __restrict__ Ws,
                                                   const float* __restrict__ Wn,
                                                   unsigned short* __restrict__ Wfrag,
                                                   int* __restrict__ deg,
                                                   int castB, int n8, int N) {
    int bid = blockIdx.x;
    int t   = threadIdx.x;
    if (bid < castB) {
        int i = bid * 256 + t;
        if (i >= n8) return;
        const float4* s = (const float4*)(feat + (size_t)i * 8);
        float4 a = s[0];
        float4 b = s[1];
        unsigned short pk[8];
        pk[0] = f2bf(a.x); pk[1] = f2bf(a.y); pk[2] = f2bf(a.z); pk[3] = f2bf(a.w);
        pk[4] = f2bf(b.x); pk[5] = f2bf(b.y); pk[6] = f2bf(b.z); pk[7] = f2bf(b.w);
        *(bf16x8*)(fb + (size_t)i * 8) = *(const bf16x8*)pk;
    } else if (bid < castB + 16) {
        // Wfrag[((nt*8+ks)*64 + lane)*8 + j] = bf16(Wcat[ks*32+quad*8+j][nt*16+lo16])
        int tid = (bid - castB) * 256 + t;      // 0..4095
        int l  = tid & 63;
        int ks = (tid >> 6) & 7;
        int nt = tid >> 9;
        int n  = nt * 16 + (l & 15);
        int kb = ks * 32 + (l >> 4) * 8;
        unsigned short pk[8];
#pragma unroll
        for (int j = 0; j < 8; ++j) {
            int k = kb + j;
            float w = (k < 128) ? Ws[k * D + n] : Wn[(k - 128) * D + n];
            pk[j] = f2bf(w);
        }
        *(bf16x8*)(Wfrag + (size_t)tid * 8) = *(const bf16x8*)pk;
    } else {
        int i = (bid - castB - 16) * 256 + t;
        if (i < N) deg[i] = 0;
        if (bid == castB + 16 && t < 64)
            ((unsigned int*)(fb + (size_t)N * D))[t] = 0;   // zero dummy row
    }
}

// ---------------------------------------------------------------- edge scatter
// One pass, no staging: per edge, claim a slot in dst's fixed 64-entry bucket.
// deg[] doubles as the per-node cursor and the final in-degree.
__global__ __launch_bounds__(256) void edge_kernel(const int* __restrict__ src,
                                                   const int* __restrict__ dst,
                                                   int* __restrict__ deg,
                                                   unsigned short* __restrict__ bucket,
                                                   int E) {
    int e = blockIdx.x * 256 + threadIdx.x;
    if (e >= E) return;
    int d = dst[e];
    int s = src[e];
    int loc = atomicAdd(&deg[d], 1);
    if (loc < CAPN)
        bucket[(size_t)d * CAPN + loc] = (unsigned short)s;
}

// ---------------------------------------------------------------- fused gather + MFMA
// One block = 4 waves (256 thr) = 16 nodes; wave w gathers nodes [v0+w*4, +4).
// WHOLE-WAVE-PER-EDGE mapping: lane l reads the dword at cols {2l, 2l+1} of
// each edge row (64 lanes x 4B = full 256B row, coalesced). Lane owns its two
// columns across ALL edges -> NO cross-lane reduce, no bpermutes, no exec-mask
// hazards (all control wave-uniform; R4 lesson). Edge indices come from
// readlane on the prefetched 64-slot bucket row (SGPR row base -> saddr
// loads); slots >= d redirect via uniform cselect to the zero row fb[N]
// (branch-free, all 16 chunk loads issued back-to-back = 16-deep MLP vs
// R5's 4-deep). Phase-2 self A-frags prefetched before the gather.
// Phase 2: out[16,128] = [fb | hL] @ Wcat + b; wave w owns cols [w*32, +32):
// 8 ks x 2 nt MFMAs. B-frags from Wfrag (L2-hot).
__global__ __launch_bounds__(256) void gather_mfma_kernel(
        const unsigned short* __restrict__ fb,
        const unsigned short* __restrict__ bucket,
        const int* __restrict__ deg,
        const unsigned short* __restrict__ Wfrag,
        const float* __restrict__ bias,
        float* __restrict__ out, int N) {
    __shared__ unsigned short hL[16 * HPAD];

    int t    = threadIdx.x;
    int w    = t >> 6;
    int lane = t & 63;
    int lo16 = lane & 15;
    int quad = lane >> 4;
    int v0   = blockIdx.x * 16;
    int n0   = v0 + w * 4;

    // prefetch phase-2 self A-frags (independent of gather; hidden under it)
    int rowA = v0 + lo16;
    if (rowA > N - 1) rowA = N - 1;           // clamp; stores guarded below
    bf16x8 aself[4];
#pragma unroll
    for (int ks = 0; ks < 4; ++ks)
        aself[ks] = *(const bf16x8*)(fb + (size_t)rowA * D + ks * 32 + quad * 8);

    // lanes 0..3 hold deg of nodes n0..n0+3 (replicated every 4 lanes)
    int nd  = n0 + (lane & 3);
    int dn  = (nd < N) ? deg[nd] : 0;
    int idx_cur = (n0 < N) ? (int)bucket[(size_t)n0 * CAPN + lane] : 0;

    for (int nn = 0; nn < 4; ++nn) {
        int node  = n0 + nn;                    // wave-uniform
        int dtrue = __shfl(dn, nn);
        int d     = (node < N) ? dtrue : 0;
        if (d > CAPN) d = CAPN;
        // prefetch next node's index row during this node's accumulation
        int idx_next = (nn < 3 && node + 1 < N)
                     ? (int)bucket[(size_t)(node + 1) * CAPN + lane] : 0;

        float a0 = 0.f, a1 = 0.f;
        for (int e0 = 0; e0 < d; e0 += 16) {
            unsigned int x[16];
#pragma unroll
            for (int j = 0; j < 16; ++j) {
                int ue = __builtin_amdgcn_readlane(idx_cur, e0 + j);  // uniform
                ue = (e0 + j < d) ? ue : N;     // uniform cselect -> zero row
                x[j] = *(const unsigned int*)(fb + (size_t)ue * D + lane * 2);
            }
#pragma unroll
            for (int j = 0; j < 16; ++j) {
                a0 += bf_lo(x[j]);
                a1 += bf_hi(x[j]);
            }
        }

        float inv = (d > 0) ? 1.0f / (float)dtrue : 0.0f;
        unsigned int pk = ((unsigned int)f2bf(a1 * inv) << 16)
                        | (unsigned int)f2bf(a0 * inv);
        *(unsigned int*)&hL[(w * 4 + nn) * HPAD + lane * 2] = pk;
        idx_cur = idx_next;
    }
    __syncthreads();

    // ---- phase 2: MFMA (16 rows x 128 cols; wave w owns cols [w*32, +32)) ----
    f32x4 accO[2];
#pragma unroll
    for (int ntl = 0; ntl < 2; ++ntl) accO[ntl] = (f32x4){0.f, 0.f, 0.f, 0.f};

#pragma unroll
    for (int ks = 0; ks < 8; ++ks) {
        bf16x8 a;
        if (ks < 4)
            a = aself[ks];
        else
            a = *(const bf16x8*)&hL[lo16 * HPAD + (ks - 4) * 32 + quad * 8];
        const unsigned short* wp = Wfrag + ((size_t)ks * 64 + lane) * 8;
#pragma unroll
        for (int ntl = 0; ntl < 2; ++ntl) {
            int nt = w * 2 + ntl;
            bf16x8 b = *(const bf16x8*)(wp + (size_t)nt * 4096);
            accO[ntl] = __builtin_amdgcn_mfma_f32_16x16x32_bf16(a, b, accO[ntl], 0, 0, 0);
        }
    }

    // C/D layout: col = lane&15, row = quad*4 + reg
#pragma unroll
    for (int ntl = 0; ntl < 2; ++ntl) {
        int n = (w * 2 + ntl) * 16 + lo16;
        float bvl = bias[n];
#pragma unroll
        for (int r = 0; r < 4; ++r) {
            int row = v0 + quad * 4 + r;
            if (row < N) out[(size_t)row * D + n] = accO[ntl][r] + bvl;
        }
    }
}

extern "C" void kernel_launch(void* const* d_in, const int* in_sizes, int n_in,
                              void* d_out, int out_size, void* d_ws, size_t ws_size,
                              hipStream_t stream) {
    const float* feat = (const float*)d_in[0];
    const int*   src  = (const int*)d_in[1];
    const int*   dst  = (const int*)d_in[2];
    const float* Ws   = (const float*)d_in[3];
    const float* Wn   = (const float*)d_in[4];
    const float* bias = (const float*)d_in[5];
    float*       out  = (float*)d_out;

    const int N = in_sizes[0] / D;
    const int E = in_sizes[1];
    const int castB = (N * D / 8 + 255) / 256;
    const int zeroB = (N + 255) / 256;

    // ws layout: ints: deg[N] ; then bucket[N*CAPN] (ushort) |
    //   fb[(N+1)*D] (bf16; row N = zero dummy) | Wfrag[32768] (bf16)
    int* deg = (int*)d_ws;
    unsigned short* bucket = (unsigned short*)(deg + N);
    size_t short_count = (size_t)N * CAPN;
    short_count = (short_count + 7) & ~(size_t)7;    // 16B-align what follows
    unsigned short* fb    = bucket + short_count;
    unsigned short* Wfrag = fb + (size_t)(N + 1) * D;

    prep_kernel<<<castB + 16 + zeroB, 256, 0, stream>>>(feat, fb, Ws, Wn, Wfrag, deg,
                                                        castB, N * D / 8, N);
    edge_kernel<<<(E + 255) / 256, 256, 0, stream>>>(src, dst, deg, bucket, E);
    gather_mfma_kernel<<<(N + 15) / 16, 256, 0, stream>>>(fb, bucket, deg, Wfrag,
                                                          bias, out, N);
}

// Round 7
// 155.751 us; speedup vs baseline: 1.3869x; 1.1113x over previous
//
#include <hip/hip_runtime.h>

#define D 128
#define CAPN 64      // per-node bucket capacity (in-deg ~ Poisson(16); P(d>=64) ~ 2e-18)
#define HPAD 136     // h_neigh LDS row stride in shorts (128 + 8 pad)
#define EC 2048      // edges per binning chunk
#define BSH 8        // bin = dst >> 8 (256 nodes per bin)
#define CAP 5120     // per-bin segment capacity (avg 4082, sigma ~64; +16 sigma)
#define CSTR 16      // bin_cursor stride in ints (64B line per counter)

typedef __attribute__((ext_vector_type(8))) short bf16x8;
typedef __attribute__((ext_vector_type(4))) float f32x4;

__device__ __forceinline__ unsigned short f2bf(float f) {
    union { float f; unsigned int u; } c;
    c.f = f;
    unsigned int lsb = (c.u >> 16) & 1u;
    c.u += 0x7fffu + lsb;
    return (unsigned short)(c.u >> 16);
}

__device__ __forceinline__ float bf_lo(unsigned int x) {
    union { unsigned int u; float f; } c;
    c.u = x << 16;
    return c.f;
}
__device__ __forceinline__ float bf_hi(unsigned int x) {
    union { unsigned int u; float f; } c;
    c.u = x & 0xffff0000u;
    return c.f;
}

// ---------------------------------------------------------------- fused prep
// blocks [0, castB): cast feat -> fb (bf16)
// blocks [castB, castB+16): Wcat -> Wfrag in MFMA B-fragment order
// block castB+16: zero bin_cursor (256 x CSTR ints) + fb dummy zero row
__global__ __launch_bounds__(256) void prep_kernel(const float* __restrict__ feat,
                                                   unsigned short* __restrict__ fb,
                                                   const float* __restrict__ Ws,
                                                   const float* __restrict__ Wn,
                                                   unsigned short* __restrict__ Wfrag,
                                                   int* __restrict__ bin_cursor,
                                                   int castB, int n8, int N) {
    int bid = blockIdx.x;
    int t   = threadIdx.x;
    if (bid < castB) {
        int i = bid * 256 + t;
        if (i >= n8) return;
        const float4* s = (const float4*)(feat + (size_t)i * 8);
        float4 a = s[0];
        float4 b = s[1];
        unsigned short pk[8];
        pk[0] = f2bf(a.x); pk[1] = f2bf(a.y); pk[2] = f2bf(a.z); pk[3] = f2bf(a.w);
        pk[4] = f2bf(b.x); pk[5] = f2bf(b.y); pk[6] = f2bf(b.z); pk[7] = f2bf(b.w);
        *(bf16x8*)(fb + (size_t)i * 8) = *(const bf16x8*)pk;
    } else if (bid < castB + 16) {
        // Wfrag[((nt*8+ks)*64 + lane)*8 + j] = bf16(Wcat[ks*32+quad*8+j][nt*16+lo16])
        int tid = (bid - castB) * 256 + t;      // 0..4095
        int l  = tid & 63;
        int ks = (tid >> 6) & 7;
        int nt = tid >> 9;
        int n  = nt * 16 + (l & 15);
        int kb = ks * 32 + (l >> 4) * 8;
        unsigned short pk[8];
#pragma unroll
        for (int j = 0; j < 8; ++j) {
            int k = kb + j;
            float w = (k < 128) ? Ws[k * D + n] : Wn[(k - 128) * D + n];
            pk[j] = f2bf(w);
        }
        *(bf16x8*)(Wfrag + (size_t)tid * 8) = *(const bf16x8*)pk;
    } else {
#pragma unroll
        for (int j = 0; j < CSTR; ++j)
            bin_cursor[j * 256 + t] = 0;
        if (t < 64)
            ((unsigned int*)(fb + (size_t)N * D))[t] = 0;   // zero dummy row
    }
}

// ---------------------------------------------------------------- stage 1: bin scatter
// LDS histogram of this chunk's bins; reserve a contiguous range in bin b's
// segment (one global atomic per block-bin, line-padded cursor); write edges
// packed (dstLocal<<16 | src) in ~10-entry contiguous runs per bin ->
// ~6x less line-touch than the naive per-node 2B scatter (44 MB -> ~7 MB).
__global__ __launch_bounds__(256) void binscatter_kernel(const int* __restrict__ src,
                                                         const int* __restrict__ dst,
                                                         int* __restrict__ bin_cursor,
                                                         unsigned int* __restrict__ ebuf,
                                                         int E, int NB) {
    __shared__ int cnt[256];
    __shared__ int basev[256];
    __shared__ int cur[256];
    int t = threadIdx.x;
    cnt[t] = 0;
    cur[t] = 0;
    __syncthreads();
    int base = blockIdx.x * EC;
    int dr[EC / 256];
#pragma unroll
    for (int i = 0; i < EC / 256; ++i) {
        int e = base + i * 256 + t;
        dr[i] = (e < E) ? dst[e] : -1;
        if (dr[i] >= 0) atomicAdd(&cnt[dr[i] >> BSH], 1);
    }
    __syncthreads();
    if (t < NB && cnt[t]) basev[t] = atomicAdd(&bin_cursor[t * CSTR], cnt[t]);
    __syncthreads();
#pragma unroll
    for (int i = 0; i < EC / 256; ++i) {
        int e = base + i * 256 + t;
        if (dr[i] >= 0) {
            int d = dr[i];
            int b = d >> BSH;
            int loc = basev[b] + atomicAdd(&cur[b], 1);
            if (loc < CAP)
                ebuf[(size_t)b * CAP + loc] =
                    (unsigned int)src[e] | ((unsigned int)(d & ((1 << BSH) - 1)) << 16);
        }
    }
}

// ---------------------------------------------------------------- stage 2: bucket build
// One block per bin. Read the bin's packed segment (coalesced), LDS-scatter
// src ids into the bin's 256x64 ushort bucket image (LDS atomics, 32 KB),
// then stream the whole image out as contiguous uint4s -> fully-dirty lines,
// ZERO write amplification (this was edge_kernel's 44 MB / ~50 us cost).
// deg is written exactly (no global atomics).
__global__ __launch_bounds__(256) void csrbin_kernel(const unsigned int* __restrict__ ebuf,
                                                     const int* __restrict__ bin_cursor,
                                                     int* __restrict__ deg_g,
                                                     unsigned short* __restrict__ bucket,
                                                     int N) {
    __shared__ unsigned short lb[256 * CAPN];   // 32 KB bucket image
    __shared__ int degL[256];
    int b = blockIdx.x;
    int t = threadIdx.x;
    int cntb = bin_cursor[b * CSTR];
    if (cntb > CAP) cntb = CAP;
    int s  = b * CAP;
    int e2 = s + cntb;

    degL[t] = 0;
    __syncthreads();

    for (int i = s + t; i < e2; i += 256) {
        unsigned int p = ebuf[i];
        int dl = (p >> 16) & 255;
        int slot = atomicAdd(&degL[dl], 1);
        if (slot < CAPN)
            lb[dl * CAPN + slot] = (unsigned short)(p & 0xffffu);
    }
    __syncthreads();

    int node = (b << BSH) + t;
    if (node < N) deg_g[node] = degL[t];

    // coalesced copy-out: 256*CAPN ushorts = 2048 uint4s, 8 per thread
    uint4* dstq = (uint4*)(bucket + (size_t)b * 256 * CAPN);
    const uint4* srcq = (const uint4*)lb;
#pragma unroll
    for (int k = 0; k < (256 * CAPN) / 8 / 256; ++k)
        dstq[k * 256 + t] = srcq[k * 256 + t];
}

// ---------------------------------------------------------------- fused gather + MFMA
// (unchanged from R6) One block = 4 waves = 16 nodes; wave w gathers nodes
// [v0+w*4, +4). Whole-wave-per-edge: lane l owns cols {2l,2l+1}; no cross-lane
// reduce; edge indices via readlane on the prefetched 64-slot bucket row;
// slots >= d redirect (uniform cselect) to the zero row fb[N]; 16 loads in
// flight per chunk. Phase-2 self A-frags prefetched before the gather.
__global__ __launch_bounds__(256) void gather_mfma_kernel(
        const unsigned short* __restrict__ fb,
        const unsigned short* __restrict__ bucket,
        const int* __restrict__ deg,
        const unsigned short* __restrict__ Wfrag,
        const float* __restrict__ bias,
        float* __restrict__ out, int N) {
    __shared__ unsigned short hL[16 * HPAD];

    int t    = threadIdx.x;
    int w    = t >> 6;
    int lane = t & 63;
    int lo16 = lane & 15;
    int quad = lane >> 4;
    int v0   = blockIdx.x * 16;
    int n0   = v0 + w * 4;

    // prefetch phase-2 self A-frags (independent of gather; hidden under it)
    int rowA = v0 + lo16;
    if (rowA > N - 1) rowA = N - 1;           // clamp; stores guarded below
    bf16x8 aself[4];
#pragma unroll
    for (int ks = 0; ks < 4; ++ks)
        aself[ks] = *(const bf16x8*)(fb + (size_t)rowA * D + ks * 32 + quad * 8);

    // lanes 0..3 hold deg of nodes n0..n0+3 (replicated every 4 lanes)
    int nd  = n0 + (lane & 3);
    int dn  = (nd < N) ? deg[nd] : 0;
    int idx_cur = (n0 < N) ? (int)bucket[(size_t)n0 * CAPN + lane] : 0;

    for (int nn = 0; nn < 4; ++nn) {
        int node  = n0 + nn;                    // wave-uniform
        int dtrue = __shfl(dn, nn);
        int d     = (node < N) ? dtrue : 0;
        if (d > CAPN) d = CAPN;
        // prefetch next node's index row during this node's accumulation
        int idx_next = (nn < 3 && node + 1 < N)
                     ? (int)bucket[(size_t)(node + 1) * CAPN + lane] : 0;

        float a0 = 0.f, a1 = 0.f;
        for (int e0 = 0; e0 < d; e0 += 16) {
            unsigned int x[16];
#pragma unroll
            for (int j = 0; j < 16; ++j) {
                int ue = __builtin_amdgcn_readlane(idx_cur, e0 + j);  // uniform
                ue = (e0 + j < d) ? ue : N;     // uniform cselect -> zero row
                x[j] = *(const unsigned int*)(fb + (size_t)ue * D + lane * 2);
            }
#pragma unroll
            for (int j = 0; j < 16; ++j) {
                a0 += bf_lo(x[j]);
                a1 += bf_hi(x[j]);
            }
        }

        float inv = (d > 0) ? 1.0f / (float)dtrue : 0.0f;
        unsigned int pk = ((unsigned int)f2bf(a1 * inv) << 16)
                        | (unsigned int)f2bf(a0 * inv);
        *(unsigned int*)&hL[(w * 4 + nn) * HPAD + lane * 2] = pk;
        idx_cur = idx_next;
    }
    __syncthreads();

    // ---- phase 2: MFMA (16 rows x 128 cols; wave w owns cols [w*32, +32)) ----
    f32x4 accO[2];
#pragma unroll
    for (int ntl = 0; ntl < 2; ++ntl) accO[ntl] = (f32x4){0.f, 0.f, 0.f, 0.f};

#pragma unroll
    for (int ks = 0; ks < 8; ++ks) {
        bf16x8 a;
        if (ks < 4)
            a = aself[ks];
        else
            a = *(const bf16x8*)&hL[lo16 * HPAD + (ks - 4) * 32 + quad * 8];
        const unsigned short* wp = Wfrag + ((size_t)ks * 64 + lane) * 8;
#pragma unroll
        for (int ntl = 0; ntl < 2; ++ntl) {
            int nt = w * 2 + ntl;
            bf16x8 b = *(const bf16x8*)(wp + (size_t)nt * 4096);
            accO[ntl] = __builtin_amdgcn_mfma_f32_16x16x32_bf16(a, b, accO[ntl], 0, 0, 0);
        }
    }

    // C/D layout: col = lane&15, row = quad*4 + reg
#pragma unroll
    for (int ntl = 0; ntl < 2; ++ntl) {
        int n = (w * 2 + ntl) * 16 + lo16;
        float bvl = bias[n];
#pragma unroll
        for (int r = 0; r < 4; ++r) {
            int row = v0 + quad * 4 + r;
            if (row < N) out[(size_t)row * D + n] = accO[ntl][r] + bvl;
        }
    }
}

extern "C" void kernel_launch(void* const* d_in, const int* in_sizes, int n_in,
                              void* d_out, int out_size, void* d_ws, size_t ws_size,
                              hipStream_t stream) {
    const float* feat = (const float*)d_in[0];
    const int*   src  = (const int*)d_in[1];
    const int*   dst  = (const int*)d_in[2];
    const float* Ws   = (const float*)d_in[3];
    const float* Wn   = (const float*)d_in[4];
    const float* bias = (const float*)d_in[5];
    float*       out  = (float*)d_out;

    const int N  = in_sizes[0] / D;
    const int E  = in_sizes[1];
    const int NB = (N + (1 << BSH) - 1) >> BSH;      // bins of 256 nodes
    const int nchunk = (E + EC - 1) / EC;
    const int castB  = (N * D / 8 + 255) / 256;

    // ws layout: ints: bin_cursor[256*CSTR] | deg[N] | ebuf[NB*CAP] ;
    //   then bucket[NB*256*CAPN] (ushort) | fb[(N+1)*D] (bf16; row N = zero) |
    //   Wfrag[32768] (bf16)
    int* bin_cursor = (int*)d_ws;
    int* deg        = bin_cursor + 256 * CSTR;
    unsigned int* ebuf = (unsigned int*)(deg + N);
    unsigned short* bucket = (unsigned short*)(ebuf + (size_t)NB * CAP);
    size_t short_count = (size_t)NB * 256 * CAPN;
    short_count = (short_count + 7) & ~(size_t)7;    // 16B-align what follows
    unsigned short* fb    = bucket + short_count;
    unsigned short* Wfrag = fb + (size_t)(N + 1) * D;

    prep_kernel<<<castB + 17, 256, 0, stream>>>(feat, fb, Ws, Wn, Wfrag, bin_cursor,
                                                castB, N * D / 8, N);
    binscatter_kernel<<<nchunk, 256, 0, stream>>>(src, dst, bin_cursor, ebuf, E, NB);
    csrbin_kernel<<<NB, 256, 0, stream>>>(ebuf, bin_cursor, deg, bucket, N);
    gather_mfma_kernel<<<(N + 15) / 16, 256, 0, stream>>>(fb, bucket, deg, Wfrag,
                                                          bias, out, N);
}